// Round 12
// baseline (645.834 us; speedup 1.0000x reference)
//
#include <hip/hip_runtime.h>
#include <hip/hip_bf16.h>

#define NN 100000
#define NE 1600000
#define FN 64
#define FE 32
#define EPS 1e-5f
#define SAMPLE 16
#define SAMPLED_E (NE / SAMPLE)
#define GNODES 8
#define NGROUP (NN / GNODES)
#define CHUNK 98                    // ceil(NN / 1024)

typedef __attribute__((ext_vector_type(8))) short bf16x8;
typedef __attribute__((ext_vector_type(4))) float f32x4;

__device__ __forceinline__ float softplus_f(float x) {
    return log1pf(expf(-fabsf(x))) + fmaxf(x, 0.0f);
}
__device__ __forceinline__ float sigmoid_fast(float x) {
    return __builtin_amdgcn_rcpf(1.0f + __expf(-x));
}
__device__ __forceinline__ float softplus_fast(float x) {
    return __logf(1.0f + __expf(-fabsf(x))) + fmaxf(x, 0.0f);
}
__device__ __forceinline__ short f2bf(float f) {
    __hip_bfloat16 h = __float2bfloat16(f);
    return *reinterpret_cast<short*>(&h);
}
__device__ __forceinline__ unsigned pack_bf2(float lo, float hi) {
    __hip_bfloat162 t = __float22bfloat162_rn(float2{lo, hi});
    return *(unsigned*)&t;
}
__device__ __forceinline__ float bflo(unsigned w) { return __uint_as_float(w << 16); }
__device__ __forceinline__ float bfhi(unsigned w) { return __uint_as_float(w & 0xffff0000u); }

// st layout: 0:s_i 64:ss_i 128:s_u 192:ss_u 256:sc_i 320:sh_i 384:sc_u 448:sh_u
//            512:s_bn 576:ss_bn 640:a_bn 704:c_bn

// ---------- node precompute (MFMA) + fused dst-histogram ----------
__global__ __launch_bounds__(256) void k_nodes_mfma(
    const float* __restrict__ nf,
    const float* __restrict__ Wi, const float* __restrict__ Wu,
    const float* __restrict__ bi, const float* __restrict__ bu,
    const int* __restrict__ dst,            // for fused histogram (null -> skip)
    unsigned* __restrict__ cnt,
    unsigned* __restrict__ P, unsigned* __restrict__ Q)
{
    const int lane = threadIdx.x & 63;
    const int l15 = lane & 15;
    const int lh  = lane >> 4;
    const int wave = threadIdx.x >> 6;
    const long wid = (long)blockIdx.x * 4 + wave;
    const long nwaves = (long)gridDim.x * 4;

    // fused histogram (independent of GEMM; overlaps with memory-bound main loop)
    if (cnt != nullptr) {
        long i = (long)blockIdx.x * blockDim.x + threadIdx.x;
        long stride = (long)gridDim.x * blockDim.x;
        for (long e = i; e < NE / 4; e += stride) {
            int4 d = ((const int4*)dst)[e];
            atomicAdd(&cnt[d.x], 1u);
            atomicAdd(&cnt[d.y], 1u);
            atomicAdd(&cnt[d.z], 1u);
            atomicAdd(&cnt[d.w], 1u);
        }
    }

    bf16x8 B[2][2][4][2];
    #pragma unroll
    for (int mi = 0; mi < 2; ++mi) {
        const float* W = mi ? Wu : Wi;
        #pragma unroll
        for (int h = 0; h < 2; ++h)
        #pragma unroll
        for (int c = 0; c < 4; ++c)
        #pragma unroll
        for (int ks = 0; ks < 2; ++ks)
        #pragma unroll
        for (int j = 0; j < 8; ++j) {
            int row = h * 64 + ks * 32 + lh * 8 + j;
            int col = c * 16 + l15;
            B[mi][h][c][ks][j] = f2bf(W[row * 64 + col]);
        }
    }
    float bic[4], buc[4];
    #pragma unroll
    for (int c = 0; c < 4; ++c) { bic[c] = bi[c * 16 + l15]; buc[c] = bu[c * 16 + l15]; }

    const f32x4 zero = {0.f, 0.f, 0.f, 0.f};
    for (long g = wid; g < NN / 16; g += nwaves) {
        const long n0 = g * 16;
        const float* arow = nf + (n0 + l15) * 64 + lh * 8;
        float4 a00 = *(const float4*)(arow);
        float4 a01 = *(const float4*)(arow + 4);
        float4 a10 = *(const float4*)(arow + 32);
        float4 a11 = *(const float4*)(arow + 36);
        bf16x8 A0, A1;
        A0[0] = f2bf(a00.x); A0[1] = f2bf(a00.y); A0[2] = f2bf(a00.z); A0[3] = f2bf(a00.w);
        A0[4] = f2bf(a01.x); A0[5] = f2bf(a01.y); A0[6] = f2bf(a01.z); A0[7] = f2bf(a01.w);
        A1[0] = f2bf(a10.x); A1[1] = f2bf(a10.y); A1[2] = f2bf(a10.z); A1[3] = f2bf(a10.w);
        A1[4] = f2bf(a11.x); A1[5] = f2bf(a11.y); A1[6] = f2bf(a11.z); A1[7] = f2bf(a11.w);

        f32x4 acc[2][2][4];
        #pragma unroll
        for (int mi = 0; mi < 2; ++mi)
        #pragma unroll
        for (int h = 0; h < 2; ++h)
        #pragma unroll
        for (int c = 0; c < 4; ++c) {
            f32x4 t = __builtin_amdgcn_mfma_f32_16x16x32_bf16(A0, B[mi][h][c][0], zero, 0, 0, 0);
            acc[mi][h][c] = __builtin_amdgcn_mfma_f32_16x16x32_bf16(A1, B[mi][h][c][1], t, 0, 0, 0);
        }
        #pragma unroll
        for (int r = 0; r < 4; ++r) {
            uint4 wp, wq;
            unsigned* pw = (unsigned*)&wp;
            unsigned* qw = (unsigned*)&wq;
            #pragma unroll
            for (int c = 0; c < 4; ++c) {
                pw[c] = pack_bf2(acc[0][0][c][r] + bic[c], acc[1][0][c][r] + buc[c]);
                qw[c] = pack_bf2(acc[0][1][c][r], acc[1][1][c][r]);
            }
            *(uint4*)(P + (n0 + lh * 4 + r) * 64 + l15 * 4) = wp;
            *(uint4*)(Q + (n0 + lh * 4 + r) * 64 + l15 * 4) = wq;
        }
    }
}

// ---------- single-kernel full scan (one block, 1024 threads) ----------
__global__ __launch_bounds__(1024) void k_scan_all(unsigned* __restrict__ cnt,
                                                   unsigned* __restrict__ cur)
{
    __shared__ unsigned s[1024];
    const int t = threadIdx.x;
    const long beg = (long)t * CHUNK;
    const long end = (beg + CHUNK < NN) ? beg + CHUNK : NN;

    unsigned sum = 0;
    for (long i = beg; i < end; ++i) sum += cnt[i];
    s[t] = sum;
    __syncthreads();
    #pragma unroll
    for (int off = 1; off < 1024; off <<= 1) {
        unsigned add = (t >= off) ? s[t - off] : 0u;
        __syncthreads();
        s[t] += add;
        __syncthreads();
    }
    unsigned run = (t == 0) ? 0u : s[t - 1];
    for (long i = beg; i < end; ++i) {
        unsigned c = cnt[i];
        cnt[i] = run;
        cur[i] = run;
        run += c;
    }
    if (t == 1023) cnt[NN] = NE;      // CSR sentinel
}

// ---------- scatter: one int2 (8B) store per edge ----------
// srcSE[pos] = { src | ((dst&7)<<20), eid }
__global__ __launch_bounds__(256) void k_scatter(const int* __restrict__ src,
                                                 const int* __restrict__ dst,
                                                 unsigned* __restrict__ cur,
                                                 int2* __restrict__ srcSE)
{
    long i = (long)blockIdx.x * blockDim.x + threadIdx.x;
    long stride = (long)gridDim.x * blockDim.x;
    for (long e = i; e < NE; e += stride) {
        int s = src[e], d = dst[e];
        unsigned pos = atomicAdd(&cur[d], 1u);
        srcSE[pos] = make_int2(s | ((d & 7) << 20), (int)e);
    }
}

// ---------- flat-tile grouped-CSR apply + fused node-BN stats ----------
__global__ __launch_bounds__(256) void k_flat(
    const float* __restrict__ ef,
    const int2* __restrict__ srcSE,
    const unsigned* __restrict__ roff,
    const float* __restrict__ Wi, const float* __restrict__ Wu,
    const unsigned* __restrict__ P, const unsigned* __restrict__ Q,
    float* __restrict__ st, float* __restrict__ agg)
{
    const int lane = threadIdx.x & 63;
    const int l15 = lane & 15;
    const int lh  = lane >> 4;
    const int wave = threadIdx.x >> 6;
    const int wid = blockIdx.x * 4 + wave;
    const int nwaves = gridDim.x * 4;

    __shared__ float slab[4][GNODES][64];
    __shared__ float red[256][2];

    bf16x8 Bi[4], Bu[4];
    #pragma unroll
    for (int c = 0; c < 4; ++c) {
        #pragma unroll
        for (int j = 0; j < 8; ++j) {
            int row = 128 + lh * 8 + j;
            int col = c * 16 + l15;
            Bi[c][j] = f2bf(Wi[row * 64 + col]);
            Bu[c][j] = f2bf(Wu[row * 64 + col]);
        }
    }
    float sci[4], shi[4], scu[4], shu[4];
    #pragma unroll
    for (int c = 0; c < 4; ++c) {
        int col = c * 16 + l15;
        sci[c] = st[256 + col]; shi[c] = st[320 + col];
        scu[c] = st[384 + col]; shu[c] = st[448 + col];
    }

    float sb = 0.f, ssb = 0.f;
    const f32x4 zero = {0.f, 0.f, 0.f, 0.f};

    for (int g = wid; g < NGROUP; g += nwaves) {
        const int n0 = g * GNODES;

        #pragma unroll
        for (int k = 0; k < GNODES; ++k) slab[wave][k][lane] = 0.f;

        const int lo = (int)roff[n0];
        const int hi = (int)roff[n0 + GNODES];

        if (lo < hi) {
            const int hiM1 = hi - 1;
            const int ntile = (hi - lo + 15) >> 4;

            int sC[4], eidC;
            uint4 pvC[4];
            float4 efC0, efC1;
            {
                #pragma unroll
                for (int r = 0; r < 4; ++r) {
                    int e = lo + lh * 4 + r;
                    sC[r] = srcSE[e < hi ? e : hiM1].x;
                }
                int ei = lo + l15;
                eidC = srcSE[ei < hi ? ei : hiM1].y;
                #pragma unroll
                for (int r = 0; r < 4; ++r)
                    pvC[r] = *(const uint4*)(P + (long)(sC[r] & 0xFFFFF) * 64 + l15 * 4);
                const float* efr = ef + (long)eidC * FE + lh * 8;
                efC0 = *(const float4*)(efr);
                efC1 = *(const float4*)(efr + 4);
            }
            int sN[4], eidN;
            {
                const int base1 = (ntile > 1) ? lo + 16 : lo;
                #pragma unroll
                for (int r = 0; r < 4; ++r) {
                    int e = base1 + lh * 4 + r;
                    sN[r] = srcSE[e < hi ? e : hiM1].x;
                }
                int ei = base1 + l15;
                eidN = srcSE[ei < hi ? ei : hiM1].y;
            }

            for (int ti = 0; ti < ntile; ++ti) {
                const int base = lo + ti * 16;
                uint4 pvN[4];
                float4 efN0, efN1;
                #pragma unroll
                for (int r = 0; r < 4; ++r)
                    pvN[r] = *(const uint4*)(P + (long)(sN[r] & 0xFFFFF) * 64 + l15 * 4);
                {
                    const float* efr = ef + (long)eidN * FE + lh * 8;
                    efN0 = *(const float4*)(efr);
                    efN1 = *(const float4*)(efr + 4);
                }
                int nid[4];
                uint4 qv[4];
                #pragma unroll
                for (int r = 0; r < 4; ++r) {
                    nid[r] = (sC[r] >> 20) & 7;
                    qv[r] = *(const uint4*)(Q + (long)(n0 + nid[r]) * 64 + l15 * 4);
                }
                int sN2[4], eidN2;
                {
                    int t2 = ti + 2;
                    t2 = (t2 < ntile) ? t2 : ntile - 1;
                    const int base2 = lo + t2 * 16;
                    #pragma unroll
                    for (int r = 0; r < 4; ++r) {
                        int e = base2 + lh * 4 + r;
                        sN2[r] = srcSE[e < hi ? e : hiM1].x;
                    }
                    int ei = base2 + l15;
                    eidN2 = srcSE[ei < hi ? ei : hiM1].y;
                }

                bf16x8 A;
                A[0] = f2bf(efC0.x); A[1] = f2bf(efC0.y); A[2] = f2bf(efC0.z); A[3] = f2bf(efC0.w);
                A[4] = f2bf(efC1.x); A[5] = f2bf(efC1.y); A[6] = f2bf(efC1.z); A[7] = f2bf(efC1.w);

                float vm[4];
                #pragma unroll
                for (int r = 0; r < 4; ++r)
                    vm[r] = (base + lh * 4 + r < hi) ? 1.0f : 0.0f;
                bool f1 = (nid[1] != nid[0]);
                bool f2 = (nid[2] != nid[1]);
                bool f3 = (nid[3] != nid[2]);

                #pragma unroll
                for (int c = 0; c < 4; ++c) {
                    f32x4 Ei = __builtin_amdgcn_mfma_f32_16x16x32_bf16(A, Bi[c], zero, 0, 0, 0);
                    f32x4 Eu = __builtin_amdgcn_mfma_f32_16x16x32_bf16(A, Bu[c], zero, 0, 0, 0);
                    const int col = c * 16 + l15;
                    float av = 0.f;
                    #pragma unroll
                    for (int r = 0; r < 4; ++r) {
                        unsigned qw = ((const unsigned*)&qv[r])[c];
                        unsigned pw = ((const unsigned*)&pvC[r])[c];
                        float ai = bflo(pw) + bflo(qw) + Ei[r];
                        float au = bfhi(pw) + bfhi(qw) + Eu[r];
                        float gate = sigmoid_fast(fmaf(sci[c], ai, shi[c]));
                        float updv = softplus_fast(fmaf(scu[c], au, shu[c]));
                        float val = gate * updv * vm[r];
                        if (r == 1 && f1) { atomicAdd(&slab[wave][nid[0]][col], av); av = 0.f; }
                        if (r == 2 && f2) { atomicAdd(&slab[wave][nid[1]][col], av); av = 0.f; }
                        if (r == 3 && f3) { atomicAdd(&slab[wave][nid[2]][col], av); av = 0.f; }
                        av += val;
                    }
                    atomicAdd(&slab[wave][nid[3]][col], av);
                }

                #pragma unroll
                for (int r = 0; r < 4; ++r) { pvC[r] = pvN[r]; sC[r] = sN[r]; sN[r] = sN2[r]; }
                efC0 = efN0; efC1 = efN1;
                eidC = eidN; eidN = eidN2;
            }
        }

        #pragma unroll
        for (int k = 0; k < GNODES; ++k) {
            float v = slab[wave][k][lane];
            agg[(long)(n0 + k) * 64 + lane] = v;
            sb += v; ssb = fmaf(v, v, ssb);
        }
    }

    red[threadIdx.x][0] = sb;
    red[threadIdx.x][1] = ssb;
    __syncthreads();
    if (threadIdx.x < 64) {
        float a = 0.f, bb = 0.f;
        #pragma unroll
        for (int w = 0; w < 4; ++w) {
            a  += red[w * 64 + threadIdx.x][0];
            bb += red[w * 64 + threadIdx.x][1];
        }
        atomicAdd(&st[512 + threadIdx.x], a);
        atomicAdd(&st[576 + threadIdx.x], bb);
    }
}

// ---------- stats / fallback edge kernel (unsorted, depth-2 pipeline) ----------
template <bool STATS, int GSTRIDE>
__global__ __launch_bounds__(256) void k_edge(
    const float* __restrict__ ef,
    const int* __restrict__ src, const int* __restrict__ dst,
    const float* __restrict__ Wi, const float* __restrict__ Wu,
    const unsigned* __restrict__ P, const unsigned* __restrict__ Q,
    float* __restrict__ st, float* __restrict__ agg)
{
    const int lane = threadIdx.x & 63;
    const int l15 = lane & 15;
    const int lh  = lane >> 4;
    const int wave = threadIdx.x >> 6;
    const long wid = (long)blockIdx.x * 4 + wave;
    const long nwaves = (long)gridDim.x * 4;

    __shared__ float accs[4][64];
    if (STATS) {
        if (threadIdx.x < 256) ((float*)accs)[threadIdx.x] = 0.f;
        __syncthreads();
    }

    bf16x8 Bi[4], Bu[4];
    #pragma unroll
    for (int c = 0; c < 4; ++c) {
        #pragma unroll
        for (int j = 0; j < 8; ++j) {
            int row = 128 + lh * 8 + j;
            int col = c * 16 + l15;
            Bi[c][j] = f2bf(Wi[row * 64 + col]);
            Bu[c][j] = f2bf(Wu[row * 64 + col]);
        }
    }
    float sci[4], shi[4], scu[4], shu[4];
    #pragma unroll
    for (int c = 0; c < 4; ++c) {
        int col = c * 16 + l15;
        if (!STATS) {
            sci[c] = st[256 + col]; shi[c] = st[320 + col];
            scu[c] = st[384 + col]; shu[c] = st[448 + col];
        } else {
            sci[c] = shi[c] = scu[c] = shu[c] = 0.f;
        }
    }

    float s_i[4] = {0,0,0,0}, ss_i[4] = {0,0,0,0};
    float s_u[4] = {0,0,0,0}, ss_u[4] = {0,0,0,0};

    const long NGI = (NE / 16) / GSTRIDE;
    if (wid < NGI) {
        const long gi0 = wid;
        const long e00 = gi0 * GSTRIDE * 16;
        int4 sC = *(const int4*)(src + e00 + lh * 4);
        int4 dC = *(const int4*)(dst + e00 + lh * 4);
        uint4 pvC[4], qvC[4];
        {
            int sA[4] = {sC.x, sC.y, sC.z, sC.w};
            int dA[4] = {dC.x, dC.y, dC.z, dC.w};
            #pragma unroll
            for (int r = 0; r < 4; ++r) {
                pvC[r] = *(const uint4*)(P + (long)sA[r] * 64 + l15 * 4);
                qvC[r] = *(const uint4*)(Q + (long)dA[r] * 64 + l15 * 4);
            }
        }
        float4 efC0 = *(const float4*)(ef + (e00 + l15) * FE + lh * 8);
        float4 efC1 = *(const float4*)(ef + (e00 + l15) * FE + lh * 8 + 4);

        long g1p = gi0 + nwaves;
        long g1c = (g1p < NGI) ? g1p : gi0;
        int4 sN = *(const int4*)(src + g1c * GSTRIDE * 16 + lh * 4);
        int4 dN = *(const int4*)(dst + g1c * GSTRIDE * 16 + lh * 4);

        for (long gi = gi0; gi < NGI; gi += nwaves) {
            const long gn   = gi + nwaves;
            const long gnc  = (gn < NGI) ? gn : gi;
            const long gn2  = gn + nwaves;
            const long gn2c = (gn2 < NGI) ? gn2 : gnc;
            const long eN  = gnc * GSTRIDE * 16;
            const long eN2 = gn2c * GSTRIDE * 16;

            uint4 pvN[4], qvN[4];
            {
                int sA[4] = {sN.x, sN.y, sN.z, sN.w};
                int dA[4] = {dN.x, dN.y, dN.z, dN.w};
                #pragma unroll
                for (int r = 0; r < 4; ++r) {
                    pvN[r] = *(const uint4*)(P + (long)sA[r] * 64 + l15 * 4);
                    qvN[r] = *(const uint4*)(Q + (long)dA[r] * 64 + l15 * 4);
                }
            }
            float4 efN0 = *(const float4*)(ef + (eN + l15) * FE + lh * 8);
            float4 efN1 = *(const float4*)(ef + (eN + l15) * FE + lh * 8 + 4);
            int4 sN2 = *(const int4*)(src + eN2 + lh * 4);
            int4 dN2 = *(const int4*)(dst + eN2 + lh * 4);

            bf16x8 A;
            A[0] = f2bf(efC0.x); A[1] = f2bf(efC0.y); A[2] = f2bf(efC0.z); A[3] = f2bf(efC0.w);
            A[4] = f2bf(efC1.x); A[5] = f2bf(efC1.y); A[6] = f2bf(efC1.z); A[7] = f2bf(efC1.w);
            int dApply[4] = {dC.x, dC.y, dC.z, dC.w};

            const f32x4 zero = {0.f, 0.f, 0.f, 0.f};
            #pragma unroll
            for (int c = 0; c < 4; ++c) {
                f32x4 Ei = __builtin_amdgcn_mfma_f32_16x16x32_bf16(A, Bi[c], zero, 0, 0, 0);
                f32x4 Eu = __builtin_amdgcn_mfma_f32_16x16x32_bf16(A, Bu[c], zero, 0, 0, 0);
                #pragma unroll
                for (int r = 0; r < 4; ++r) {
                    unsigned pw = ((const unsigned*)&pvC[r])[c];
                    unsigned qw = ((const unsigned*)&qvC[r])[c];
                    float ai = bflo(pw) + bflo(qw) + Ei[r];
                    float au = bfhi(pw) + bfhi(qw) + Eu[r];
                    if constexpr (STATS) {
                        s_i[c] += ai; ss_i[c] = fmaf(ai, ai, ss_i[c]);
                        s_u[c] += au; ss_u[c] = fmaf(au, au, ss_u[c]);
                    } else {
                        float gate = sigmoid_fast(fmaf(sci[c], ai, shi[c]));
                        float updv = softplus_fast(fmaf(scu[c], au, shu[c]));
                        atomicAdd(&agg[(long)dApply[r] * 64 + c * 16 + l15], gate * updv);
                    }
                }
            }

            #pragma unroll
            for (int r = 0; r < 4; ++r) { pvC[r] = pvN[r]; qvC[r] = qvN[r]; }
            efC0 = efN0; efC1 = efN1;
            dC = dN;
            sN = sN2; dN = dN2;
        }
    }

    if (STATS) {
        #pragma unroll
        for (int c = 0; c < 4; ++c) {
            int col = c * 16 + l15;
            atomicAdd(&accs[0][col], s_i[c]);
            atomicAdd(&accs[1][col], ss_i[c]);
            atomicAdd(&accs[2][col], s_u[c]);
            atomicAdd(&accs[3][col], ss_u[c]);
        }
        __syncthreads();
        {
            int stn = threadIdx.x >> 6, col = threadIdx.x & 63;
            atomicAdd(&st[stn * 64 + col], accs[stn][col]);
        }
    }
}

// ---------- small kernels ----------
__global__ void k_bn_edge(const float* __restrict__ g_i, const float* __restrict__ be_i,
                          const float* __restrict__ g_u, const float* __restrict__ be_u,
                          float* __restrict__ st)
{
    int j = threadIdx.x & 63;
    int br = threadIdx.x >> 6;
    const float invE = 1.0f / (float)SAMPLED_E;
    float s  = st[br * 128 + j];
    float ss = st[br * 128 + 64 + j];
    float mu = s * invE;
    float var = ss * invE - mu * mu;
    float inv = rsqrtf(var + EPS);
    float g  = br ? g_u[j]  : g_i[j];
    float be = br ? be_u[j] : be_i[j];
    float a = g * inv;
    st[256 + br * 128 + j]      = a;
    st[256 + br * 128 + 64 + j] = be - a * mu;
}

__global__ __launch_bounds__(256) void k_node_stats(const float* __restrict__ agg,
                                                    float* __restrict__ st)
{
    int lane = threadIdx.x & 63;
    int wave = threadIdx.x >> 6;
    float s = 0.f, ss = 0.f;
    for (long r = (long)blockIdx.x * 4 + wave; r < NN; r += (long)gridDim.x * 4) {
        float v = agg[r * 64 + lane];
        s += v; ss += v * v;
    }
    __shared__ float red[256][2];
    red[threadIdx.x][0] = s; red[threadIdx.x][1] = ss;
    __syncthreads();
    if (threadIdx.x < 64) {
        float a = 0.f, b = 0.f;
        for (int w = 0; w < 4; ++w) {
            a += red[w * 64 + threadIdx.x][0];
            b += red[w * 64 + threadIdx.x][1];
        }
        atomicAdd(&st[512 + threadIdx.x], a);
        atomicAdd(&st[576 + threadIdx.x], b);
    }
}

__global__ void k_bn_node(const float* __restrict__ g_bn, const float* __restrict__ be_bn,
                          float* __restrict__ st)
{
    int j = threadIdx.x;
    if (j >= 64) return;
    const float invN = 1.0f / (float)NN;
    float mu = st[512 + j] * invN;
    float var = st[576 + j] * invN - mu * mu;
    float a = g_bn[j] * rsqrtf(var + EPS);
    st[640 + j] = a;
    st[704 + j] = be_bn[j] - a * mu;
}

__global__ __launch_bounds__(256) void k_final4(const float4* __restrict__ nf4,
                                                float4* __restrict__ io4,
                                                const float* __restrict__ st)
{
    long i = (long)blockIdx.x * blockDim.x + threadIdx.x;
    if (i >= (long)NN * 16) return;
    int j4 = ((int)i & 15) * 4;
    float4 n = nf4[i];
    float4 v = io4[i];
    float4 o;
    o.x = softplus_f(n.x + fmaf(st[640 + j4 + 0], v.x, st[704 + j4 + 0]));
    o.y = softplus_f(n.y + fmaf(st[640 + j4 + 1], v.y, st[704 + j4 + 1]));
    o.z = softplus_f(n.z + fmaf(st[640 + j4 + 2], v.z, st[704 + j4 + 2]));
    o.w = softplus_f(n.w + fmaf(st[640 + j4 + 3], v.w, st[704 + j4 + 3]));
    io4[i] = o;
}

extern "C" void kernel_launch(void* const* d_in, const int* in_sizes, int n_in,
                              void* d_out, int out_size, void* d_ws, size_t ws_size,
                              hipStream_t stream) {
    const float* nf  = (const float*)d_in[0];
    const float* ef  = (const float*)d_in[1];
    const int*   src = (const int*)d_in[2];
    const int*   dst = (const int*)d_in[3];
    const float* Wi  = (const float*)d_in[4];
    const float* bi  = (const float*)d_in[5];
    const float* gi  = (const float*)d_in[6];
    const float* bei = (const float*)d_in[7];
    const float* Wu  = (const float*)d_in[8];
    const float* bu  = (const float*)d_in[9];
    const float* gu  = (const float*)d_in[10];
    const float* beu = (const float*)d_in[11];
    const float* gbn = (const float*)d_in[12];
    const float* bebn= (const float*)d_in[13];
    float* out = (float*)d_out;

    // ws (u32 units): P[NN*64] Q[NN*64] st[1024] cnt[NN+8] cur[NN] srcSE[2*(NE+16)]
    unsigned* P    = (unsigned*)d_ws;
    unsigned* Q    = P + (size_t)NN * 64;
    float*    st   = (float*)(Q + (size_t)NN * 64);
    unsigned* cnt  = (unsigned*)(st + 1024);
    unsigned* cur  = cnt + (NN + 8);
    int2* srcSE = (int2*)(cur + NN);

    const size_t NEEDED_CSR =
        ((size_t)NN * 128 + 1024 + (NN + 8) + NN + 2 * ((size_t)NE + 16)) * 4;
    const bool use_csr = (ws_size >= NEEDED_CSR);

    hipMemsetAsync(st, 0, 1024 * sizeof(float), stream);

    if (use_csr) {
        hipMemsetAsync(cnt, 0, (size_t)(NN + 8) * sizeof(unsigned), stream);
        k_nodes_mfma<<<512, 256, 0, stream>>>(nf, Wi, Wu, bi, bu, dst, cnt, P, Q);
        k_scan_all<<<1, 1024, 0, stream>>>(cnt, cur);
        k_scatter<<<1024, 256, 0, stream>>>(src, dst, cur, srcSE);
        k_edge<true, SAMPLE><<<1024, 256, 0, stream>>>(ef, src, dst, Wi, Wu, P, Q, st, out);
        k_bn_edge<<<1, 128, 0, stream>>>(gi, bei, gu, beu, st);
        k_flat<<<(NGROUP + 3) / 4, 256, 0, stream>>>(ef, srcSE, cnt, Wi, Wu, P, Q, st, out);
        k_bn_node<<<1, 64, 0, stream>>>(gbn, bebn, st);
    } else {
        k_nodes_mfma<<<512, 256, 0, stream>>>(nf, Wi, Wu, bi, bu, nullptr, nullptr, P, Q);
        hipMemsetAsync(d_out, 0, (size_t)out_size * sizeof(float), stream);
        k_edge<true, SAMPLE><<<1024, 256, 0, stream>>>(ef, src, dst, Wi, Wu, P, Q, st, out);
        k_bn_edge<<<1, 128, 0, stream>>>(gi, bei, gu, beu, st);
        k_edge<false, 1><<<2048, 256, 0, stream>>>(ef, src, dst, Wi, Wu, P, Q, st, out);
        k_node_stats<<<512, 256, 0, stream>>>(out, st);
        k_bn_node<<<1, 64, 0, stream>>>(gbn, bebn, st);
    }

    long tot4 = (long)NN * 16;
    k_final4<<<(int)((tot4 + 255) / 256), 256, 0, stream>>>(
        (const float4*)nf, (float4*)out, st);
}

// Round 13
// 478.459 us; speedup vs baseline: 1.3498x; 1.3498x over previous
//
#include <hip/hip_runtime.h>
#include <hip/hip_bf16.h>

#define NN 100000
#define NE 1600000
#define FN 64
#define FE 32
#define EPS 1e-5f
#define SAMPLE 16
#define SAMPLED_E (NE / SAMPLE)
#define SCAN_NB 98
#define GNODES 8
#define NGROUP (NN / GNODES)

typedef __attribute__((ext_vector_type(8))) short bf16x8;
typedef __attribute__((ext_vector_type(4))) float f32x4;

__device__ __forceinline__ float softplus_f(float x) {
    return log1pf(expf(-fabsf(x))) + fmaxf(x, 0.0f);
}
__device__ __forceinline__ float sigmoid_fast(float x) {
    return __builtin_amdgcn_rcpf(1.0f + __expf(-x));
}
__device__ __forceinline__ float softplus_fast(float x) {
    return __logf(1.0f + __expf(-fabsf(x))) + fmaxf(x, 0.0f);
}
__device__ __forceinline__ short f2bf(float f) {
    __hip_bfloat16 h = __float2bfloat16(f);
    return *reinterpret_cast<short*>(&h);
}
__device__ __forceinline__ unsigned pack_bf2(float lo, float hi) {
    __hip_bfloat162 t = __float22bfloat162_rn(float2{lo, hi});
    return *(unsigned*)&t;
}
__device__ __forceinline__ float bflo(unsigned w) { return __uint_as_float(w << 16); }
__device__ __forceinline__ float bfhi(unsigned w) { return __uint_as_float(w & 0xffff0000u); }

// st layout: 0:s_i 64:ss_i 128:s_u 192:ss_u 256:sc_i 320:sh_i 384:sc_u 448:sh_u
//            512:s_bn 576:ss_bn 640:a_bn 704:c_bn

// ---------- node precompute (MFMA) + fused dst-histogram ----------
__global__ __launch_bounds__(256) void k_nodes_mfma(
    const float* __restrict__ nf,
    const float* __restrict__ Wi, const float* __restrict__ Wu,
    const float* __restrict__ bi, const float* __restrict__ bu,
    const int* __restrict__ dst,            // for fused histogram (null -> skip)
    unsigned* __restrict__ cnt,
    unsigned* __restrict__ P, unsigned* __restrict__ Q)
{
    const int lane = threadIdx.x & 63;
    const int l15 = lane & 15;
    const int lh  = lane >> 4;
    const int wave = threadIdx.x >> 6;
    const long wid = (long)blockIdx.x * 4 + wave;
    const long nwaves = (long)gridDim.x * 4;

    if (cnt != nullptr) {
        long i = (long)blockIdx.x * blockDim.x + threadIdx.x;
        long stride = (long)gridDim.x * blockDim.x;
        for (long e = i; e < NE / 4; e += stride) {
            int4 d = ((const int4*)dst)[e];
            atomicAdd(&cnt[d.x], 1u);
            atomicAdd(&cnt[d.y], 1u);
            atomicAdd(&cnt[d.z], 1u);
            atomicAdd(&cnt[d.w], 1u);
        }
    }

    bf16x8 B[2][2][4][2];
    #pragma unroll
    for (int mi = 0; mi < 2; ++mi) {
        const float* W = mi ? Wu : Wi;
        #pragma unroll
        for (int h = 0; h < 2; ++h)
        #pragma unroll
        for (int c = 0; c < 4; ++c)
        #pragma unroll
        for (int ks = 0; ks < 2; ++ks)
        #pragma unroll
        for (int j = 0; j < 8; ++j) {
            int row = h * 64 + ks * 32 + lh * 8 + j;
            int col = c * 16 + l15;
            B[mi][h][c][ks][j] = f2bf(W[row * 64 + col]);
        }
    }
    float bic[4], buc[4];
    #pragma unroll
    for (int c = 0; c < 4; ++c) { bic[c] = bi[c * 16 + l15]; buc[c] = bu[c * 16 + l15]; }

    const f32x4 zero = {0.f, 0.f, 0.f, 0.f};
    for (long g = wid; g < NN / 16; g += nwaves) {
        const long n0 = g * 16;
        const float* arow = nf + (n0 + l15) * 64 + lh * 8;
        float4 a00 = *(const float4*)(arow);
        float4 a01 = *(const float4*)(arow + 4);
        float4 a10 = *(const float4*)(arow + 32);
        float4 a11 = *(const float4*)(arow + 36);
        bf16x8 A0, A1;
        A0[0] = f2bf(a00.x); A0[1] = f2bf(a00.y); A0[2] = f2bf(a00.z); A0[3] = f2bf(a00.w);
        A0[4] = f2bf(a01.x); A0[5] = f2bf(a01.y); A0[6] = f2bf(a01.z); A0[7] = f2bf(a01.w);
        A1[0] = f2bf(a10.x); A1[1] = f2bf(a10.y); A1[2] = f2bf(a10.z); A1[3] = f2bf(a10.w);
        A1[4] = f2bf(a11.x); A1[5] = f2bf(a11.y); A1[6] = f2bf(a11.z); A1[7] = f2bf(a11.w);

        f32x4 acc[2][2][4];
        #pragma unroll
        for (int mi = 0; mi < 2; ++mi)
        #pragma unroll
        for (int h = 0; h < 2; ++h)
        #pragma unroll
        for (int c = 0; c < 4; ++c) {
            f32x4 t = __builtin_amdgcn_mfma_f32_16x16x32_bf16(A0, B[mi][h][c][0], zero, 0, 0, 0);
            acc[mi][h][c] = __builtin_amdgcn_mfma_f32_16x16x32_bf16(A1, B[mi][h][c][1], t, 0, 0, 0);
        }
        #pragma unroll
        for (int r = 0; r < 4; ++r) {
            uint4 wp, wq;
            unsigned* pw = (unsigned*)&wp;
            unsigned* qw = (unsigned*)&wq;
            #pragma unroll
            for (int c = 0; c < 4; ++c) {
                pw[c] = pack_bf2(acc[0][0][c][r] + bic[c], acc[1][0][c][r] + buc[c]);
                qw[c] = pack_bf2(acc[0][1][c][r], acc[1][1][c][r]);
            }
            *(uint4*)(P + (n0 + lh * 4 + r) * 64 + l15 * 4) = wp;
            *(uint4*)(Q + (n0 + lh * 4 + r) * 64 + l15 * 4) = wq;
        }
    }
}

// ---------- multi-block scan (proven r11 structure) ----------
__global__ __launch_bounds__(1024) void k_scan1(unsigned* __restrict__ cnt,
                                                unsigned* __restrict__ bsum)
{
    __shared__ unsigned s[1024];
    int t = threadIdx.x;
    long idx = (long)blockIdx.x * 1024 + t;
    unsigned v = (idx < NN) ? cnt[idx] : 0u;
    s[t] = v;
    __syncthreads();
    #pragma unroll
    for (int off = 1; off < 1024; off <<= 1) {
        unsigned add = (t >= off) ? s[t - off] : 0u;
        __syncthreads();
        s[t] += add;
        __syncthreads();
    }
    if (idx < NN) cnt[idx] = s[t] - v;
    if (t == 1023) bsum[blockIdx.x] = s[1023];
}

__global__ void k_scan2(unsigned* __restrict__ bsum, unsigned* __restrict__ cnt)
{
    __shared__ unsigned s[128];
    int t = threadIdx.x;
    unsigned v = (t < SCAN_NB) ? bsum[t] : 0u;
    s[t] = v;
    __syncthreads();
    #pragma unroll
    for (int off = 1; off < 128; off <<= 1) {
        unsigned add = (t >= off) ? s[t - off] : 0u;
        __syncthreads();
        s[t] += add;
        __syncthreads();
    }
    if (t < SCAN_NB) bsum[t] = s[t] - v;
    if (t == 127) cnt[NN] = NE;             // CSR sentinel
}

__global__ __launch_bounds__(1024) void k_scan3(unsigned* __restrict__ cnt,
                                                const unsigned* __restrict__ bsum,
                                                unsigned* __restrict__ cur)
{
    long idx = (long)blockIdx.x * 1024 + threadIdx.x;
    if (idx < NN) {
        unsigned v = cnt[idx] + bsum[blockIdx.x];
        cnt[idx] = v;
        cur[idx] = v;
    }
}

// ---------- scatter: one int2 (8B) store per edge ----------
__global__ __launch_bounds__(256) void k_scatter(const int* __restrict__ src,
                                                 const int* __restrict__ dst,
                                                 unsigned* __restrict__ cur,
                                                 int2* __restrict__ srcSE)
{
    long i = (long)blockIdx.x * blockDim.x + threadIdx.x;
    long stride = (long)gridDim.x * blockDim.x;
    for (long e = i; e < NE; e += stride) {
        int s = src[e], d = dst[e];
        unsigned pos = atomicAdd(&cur[d], 1u);
        srcSE[pos] = make_int2(s | ((d & 7) << 20), (int)e);
    }
}

// ---------- flat-tile grouped-CSR apply + fused node-BN stats ----------
__global__ __launch_bounds__(256) void k_flat(
    const float* __restrict__ ef,
    const int2* __restrict__ srcSE,
    const unsigned* __restrict__ roff,
    const float* __restrict__ Wi, const float* __restrict__ Wu,
    const unsigned* __restrict__ P, const unsigned* __restrict__ Q,
    float* __restrict__ st, float* __restrict__ agg)
{
    const int lane = threadIdx.x & 63;
    const int l15 = lane & 15;
    const int lh  = lane >> 4;
    const int wave = threadIdx.x >> 6;
    const int wid = blockIdx.x * 4 + wave;
    const int nwaves = gridDim.x * 4;

    __shared__ float slab[4][GNODES][64];
    __shared__ float red[256][2];

    bf16x8 Bi[4], Bu[4];
    #pragma unroll
    for (int c = 0; c < 4; ++c) {
        #pragma unroll
        for (int j = 0; j < 8; ++j) {
            int row = 128 + lh * 8 + j;
            int col = c * 16 + l15;
            Bi[c][j] = f2bf(Wi[row * 64 + col]);
            Bu[c][j] = f2bf(Wu[row * 64 + col]);
        }
    }
    float sci[4], shi[4], scu[4], shu[4];
    #pragma unroll
    for (int c = 0; c < 4; ++c) {
        int col = c * 16 + l15;
        sci[c] = st[256 + col]; shi[c] = st[320 + col];
        scu[c] = st[384 + col]; shu[c] = st[448 + col];
    }

    float sb = 0.f, ssb = 0.f;
    const f32x4 zero = {0.f, 0.f, 0.f, 0.f};

    for (int g = wid; g < NGROUP; g += nwaves) {
        const int n0 = g * GNODES;

        #pragma unroll
        for (int k = 0; k < GNODES; ++k) slab[wave][k][lane] = 0.f;

        const int lo = (int)roff[n0];
        const int hi = (int)roff[n0 + GNODES];

        if (lo < hi) {
            const int hiM1 = hi - 1;
            const int ntile = (hi - lo + 15) >> 4;

            int sC[4], eidC;
            uint4 pvC[4];
            float4 efC0, efC1;
            {
                #pragma unroll
                for (int r = 0; r < 4; ++r) {
                    int e = lo + lh * 4 + r;
                    sC[r] = srcSE[e < hi ? e : hiM1].x;
                }
                int ei = lo + l15;
                eidC = srcSE[ei < hi ? ei : hiM1].y;
                #pragma unroll
                for (int r = 0; r < 4; ++r)
                    pvC[r] = *(const uint4*)(P + (long)(sC[r] & 0xFFFFF) * 64 + l15 * 4);
                const float* efr = ef + (long)eidC * FE + lh * 8;
                efC0 = *(const float4*)(efr);
                efC1 = *(const float4*)(efr + 4);
            }
            int sN[4], eidN;
            {
                const int base1 = (ntile > 1) ? lo + 16 : lo;
                #pragma unroll
                for (int r = 0; r < 4; ++r) {
                    int e = base1 + lh * 4 + r;
                    sN[r] = srcSE[e < hi ? e : hiM1].x;
                }
                int ei = base1 + l15;
                eidN = srcSE[ei < hi ? ei : hiM1].y;
            }

            for (int ti = 0; ti < ntile; ++ti) {
                const int base = lo + ti * 16;
                uint4 pvN[4];
                float4 efN0, efN1;
                #pragma unroll
                for (int r = 0; r < 4; ++r)
                    pvN[r] = *(const uint4*)(P + (long)(sN[r] & 0xFFFFF) * 64 + l15 * 4);
                {
                    const float* efr = ef + (long)eidN * FE + lh * 8;
                    efN0 = *(const float4*)(efr);
                    efN1 = *(const float4*)(efr + 4);
                }
                int nid[4];
                uint4 qv[4];
                #pragma unroll
                for (int r = 0; r < 4; ++r) {
                    nid[r] = (sC[r] >> 20) & 7;
                    qv[r] = *(const uint4*)(Q + (long)(n0 + nid[r]) * 64 + l15 * 4);
                }
                int sN2[4], eidN2;
                {
                    int t2 = ti + 2;
                    t2 = (t2 < ntile) ? t2 : ntile - 1;
                    const int base2 = lo + t2 * 16;
                    #pragma unroll
                    for (int r = 0; r < 4; ++r) {
                        int e = base2 + lh * 4 + r;
                        sN2[r] = srcSE[e < hi ? e : hiM1].x;
                    }
                    int ei = base2 + l15;
                    eidN2 = srcSE[ei < hi ? ei : hiM1].y;
                }

                bf16x8 A;
                A[0] = f2bf(efC0.x); A[1] = f2bf(efC0.y); A[2] = f2bf(efC0.z); A[3] = f2bf(efC0.w);
                A[4] = f2bf(efC1.x); A[5] = f2bf(efC1.y); A[6] = f2bf(efC1.z); A[7] = f2bf(efC1.w);

                float vm[4];
                #pragma unroll
                for (int r = 0; r < 4; ++r)
                    vm[r] = (base + lh * 4 + r < hi) ? 1.0f : 0.0f;
                bool f1 = (nid[1] != nid[0]);
                bool f2 = (nid[2] != nid[1]);
                bool f3 = (nid[3] != nid[2]);

                #pragma unroll
                for (int c = 0; c < 4; ++c) {
                    f32x4 Ei = __builtin_amdgcn_mfma_f32_16x16x32_bf16(A, Bi[c], zero, 0, 0, 0);
                    f32x4 Eu = __builtin_amdgcn_mfma_f32_16x16x32_bf16(A, Bu[c], zero, 0, 0, 0);
                    const int col = c * 16 + l15;
                    float av = 0.f;
                    #pragma unroll
                    for (int r = 0; r < 4; ++r) {
                        unsigned qw = ((const unsigned*)&qv[r])[c];
                        unsigned pw = ((const unsigned*)&pvC[r])[c];
                        float ai = bflo(pw) + bflo(qw) + Ei[r];
                        float au = bfhi(pw) + bfhi(qw) + Eu[r];
                        float gate = sigmoid_fast(fmaf(sci[c], ai, shi[c]));
                        float updv = softplus_fast(fmaf(scu[c], au, shu[c]));
                        float val = gate * updv * vm[r];
                        if (r == 1 && f1) { atomicAdd(&slab[wave][nid[0]][col], av); av = 0.f; }
                        if (r == 2 && f2) { atomicAdd(&slab[wave][nid[1]][col], av); av = 0.f; }
                        if (r == 3 && f3) { atomicAdd(&slab[wave][nid[2]][col], av); av = 0.f; }
                        av += val;
                    }
                    atomicAdd(&slab[wave][nid[3]][col], av);
                }

                #pragma unroll
                for (int r = 0; r < 4; ++r) { pvC[r] = pvN[r]; sC[r] = sN[r]; sN[r] = sN2[r]; }
                efC0 = efN0; efC1 = efN1;
                eidC = eidN; eidN = eidN2;
            }
        }

        #pragma unroll
        for (int k = 0; k < GNODES; ++k) {
            float v = slab[wave][k][lane];
            agg[(long)(n0 + k) * 64 + lane] = v;
            sb += v; ssb = fmaf(v, v, ssb);
        }
    }

    red[threadIdx.x][0] = sb;
    red[threadIdx.x][1] = ssb;
    __syncthreads();
    if (threadIdx.x < 64) {
        float a = 0.f, bb = 0.f;
        #pragma unroll
        for (int w = 0; w < 4; ++w) {
            a  += red[w * 64 + threadIdx.x][0];
            bb += red[w * 64 + threadIdx.x][1];
        }
        atomicAdd(&st[512 + threadIdx.x], a);
        atomicAdd(&st[576 + threadIdx.x], bb);
    }
}

// ---------- stats / fallback edge kernel (unsorted, depth-2 pipeline) ----------
template <bool STATS, int GSTRIDE>
__global__ __launch_bounds__(256) void k_edge(
    const float* __restrict__ ef,
    const int* __restrict__ src, const int* __restrict__ dst,
    const float* __restrict__ Wi, const float* __restrict__ Wu,
    const unsigned* __restrict__ P, const unsigned* __restrict__ Q,
    float* __restrict__ st, float* __restrict__ agg)
{
    const int lane = threadIdx.x & 63;
    const int l15 = lane & 15;
    const int lh  = lane >> 4;
    const int wave = threadIdx.x >> 6;
    const long wid = (long)blockIdx.x * 4 + wave;
    const long nwaves = (long)gridDim.x * 4;

    __shared__ float accs[4][64];
    if (STATS) {
        if (threadIdx.x < 256) ((float*)accs)[threadIdx.x] = 0.f;
        __syncthreads();
    }

    bf16x8 Bi[4], Bu[4];
    #pragma unroll
    for (int c = 0; c < 4; ++c) {
        #pragma unroll
        for (int j = 0; j < 8; ++j) {
            int row = 128 + lh * 8 + j;
            int col = c * 16 + l15;
            Bi[c][j] = f2bf(Wi[row * 64 + col]);
            Bu[c][j] = f2bf(Wu[row * 64 + col]);
        }
    }
    float sci[4], shi[4], scu[4], shu[4];
    #pragma unroll
    for (int c = 0; c < 4; ++c) {
        int col = c * 16 + l15;
        if (!STATS) {
            sci[c] = st[256 + col]; shi[c] = st[320 + col];
            scu[c] = st[384 + col]; shu[c] = st[448 + col];
        } else {
            sci[c] = shi[c] = scu[c] = shu[c] = 0.f;
        }
    }

    float s_i[4] = {0,0,0,0}, ss_i[4] = {0,0,0,0};
    float s_u[4] = {0,0,0,0}, ss_u[4] = {0,0,0,0};

    const long NGI = (NE / 16) / GSTRIDE;
    if (wid < NGI) {
        const long gi0 = wid;
        const long e00 = gi0 * GSTRIDE * 16;
        int4 sC = *(const int4*)(src + e00 + lh * 4);
        int4 dC = *(const int4*)(dst + e00 + lh * 4);
        uint4 pvC[4], qvC[4];
        {
            int sA[4] = {sC.x, sC.y, sC.z, sC.w};
            int dA[4] = {dC.x, dC.y, dC.z, dC.w};
            #pragma unroll
            for (int r = 0; r < 4; ++r) {
                pvC[r] = *(const uint4*)(P + (long)sA[r] * 64 + l15 * 4);
                qvC[r] = *(const uint4*)(Q + (long)dA[r] * 64 + l15 * 4);
            }
        }
        float4 efC0 = *(const float4*)(ef + (e00 + l15) * FE + lh * 8);
        float4 efC1 = *(const float4*)(ef + (e00 + l15) * FE + lh * 8 + 4);

        long g1p = gi0 + nwaves;
        long g1c = (g1p < NGI) ? g1p : gi0;
        int4 sN = *(const int4*)(src + g1c * GSTRIDE * 16 + lh * 4);
        int4 dN = *(const int4*)(dst + g1c * GSTRIDE * 16 + lh * 4);

        for (long gi = gi0; gi < NGI; gi += nwaves) {
            const long gn   = gi + nwaves;
            const long gnc  = (gn < NGI) ? gn : gi;
            const long gn2  = gn + nwaves;
            const long gn2c = (gn2 < NGI) ? gn2 : gnc;
            const long eN  = gnc * GSTRIDE * 16;
            const long eN2 = gn2c * GSTRIDE * 16;

            uint4 pvN[4], qvN[4];
            {
                int sA[4] = {sN.x, sN.y, sN.z, sN.w};
                int dA[4] = {dN.x, dN.y, dN.z, dN.w};
                #pragma unroll
                for (int r = 0; r < 4; ++r) {
                    pvN[r] = *(const uint4*)(P + (long)sA[r] * 64 + l15 * 4);
                    qvN[r] = *(const uint4*)(Q + (long)dA[r] * 64 + l15 * 4);
                }
            }
            float4 efN0 = *(const float4*)(ef + (eN + l15) * FE + lh * 8);
            float4 efN1 = *(const float4*)(ef + (eN + l15) * FE + lh * 8 + 4);
            int4 sN2 = *(const int4*)(src + eN2 + lh * 4);
            int4 dN2 = *(const int4*)(dst + eN2 + lh * 4);

            bf16x8 A;
            A[0] = f2bf(efC0.x); A[1] = f2bf(efC0.y); A[2] = f2bf(efC0.z); A[3] = f2bf(efC0.w);
            A[4] = f2bf(efC1.x); A[5] = f2bf(efC1.y); A[6] = f2bf(efC1.z); A[7] = f2bf(efC1.w);
            int dApply[4] = {dC.x, dC.y, dC.z, dC.w};

            const f32x4 zero = {0.f, 0.f, 0.f, 0.f};
            #pragma unroll
            for (int c = 0; c < 4; ++c) {
                f32x4 Ei = __builtin_amdgcn_mfma_f32_16x16x32_bf16(A, Bi[c], zero, 0, 0, 0);
                f32x4 Eu = __builtin_amdgcn_mfma_f32_16x16x32_bf16(A, Bu[c], zero, 0, 0, 0);
                #pragma unroll
                for (int r = 0; r < 4; ++r) {
                    unsigned pw = ((const unsigned*)&pvC[r])[c];
                    unsigned qw = ((const unsigned*)&qvC[r])[c];
                    float ai = bflo(pw) + bflo(qw) + Ei[r];
                    float au = bfhi(pw) + bfhi(qw) + Eu[r];
                    if constexpr (STATS) {
                        s_i[c] += ai; ss_i[c] = fmaf(ai, ai, ss_i[c]);
                        s_u[c] += au; ss_u[c] = fmaf(au, au, ss_u[c]);
                    } else {
                        float gate = sigmoid_fast(fmaf(sci[c], ai, shi[c]));
                        float updv = softplus_fast(fmaf(scu[c], au, shu[c]));
                        atomicAdd(&agg[(long)dApply[r] * 64 + c * 16 + l15], gate * updv);
                    }
                }
            }

            #pragma unroll
            for (int r = 0; r < 4; ++r) { pvC[r] = pvN[r]; qvC[r] = qvN[r]; }
            efC0 = efN0; efC1 = efN1;
            dC = dN;
            sN = sN2; dN = dN2;
        }
    }

    if (STATS) {
        #pragma unroll
        for (int c = 0; c < 4; ++c) {
            int col = c * 16 + l15;
            atomicAdd(&accs[0][col], s_i[c]);
            atomicAdd(&accs[1][col], ss_i[c]);
            atomicAdd(&accs[2][col], s_u[c]);
            atomicAdd(&accs[3][col], ss_u[c]);
        }
        __syncthreads();
        {
            int stn = threadIdx.x >> 6, col = threadIdx.x & 63;
            atomicAdd(&st[stn * 64 + col], accs[stn][col]);
        }
    }
}

// ---------- small kernels ----------
__global__ void k_bn_edge(const float* __restrict__ g_i, const float* __restrict__ be_i,
                          const float* __restrict__ g_u, const float* __restrict__ be_u,
                          float* __restrict__ st)
{
    int j = threadIdx.x & 63;
    int br = threadIdx.x >> 6;
    const float invE = 1.0f / (float)SAMPLED_E;
    float s  = st[br * 128 + j];
    float ss = st[br * 128 + 64 + j];
    float mu = s * invE;
    float var = ss * invE - mu * mu;
    float inv = rsqrtf(var + EPS);
    float g  = br ? g_u[j]  : g_i[j];
    float be = br ? be_u[j] : be_i[j];
    float a = g * inv;
    st[256 + br * 128 + j]      = a;
    st[256 + br * 128 + 64 + j] = be - a * mu;
}

__global__ __launch_bounds__(256) void k_node_stats(const float* __restrict__ agg,
                                                    float* __restrict__ st)
{
    int lane = threadIdx.x & 63;
    int wave = threadIdx.x >> 6;
    float s = 0.f, ss = 0.f;
    for (long r = (long)blockIdx.x * 4 + wave; r < NN; r += (long)gridDim.x * 4) {
        float v = agg[r * 64 + lane];
        s += v; ss += v * v;
    }
    __shared__ float red[256][2];
    red[threadIdx.x][0] = s; red[threadIdx.x][1] = ss;
    __syncthreads();
    if (threadIdx.x < 64) {
        float a = 0.f, b = 0.f;
        for (int w = 0; w < 4; ++w) {
            a += red[w * 64 + threadIdx.x][0];
            b += red[w * 64 + threadIdx.x][1];
        }
        atomicAdd(&st[512 + threadIdx.x], a);
        atomicAdd(&st[576 + threadIdx.x], b);
    }
}

__global__ void k_bn_node(const float* __restrict__ g_bn, const float* __restrict__ be_bn,
                          float* __restrict__ st)
{
    int j = threadIdx.x;
    if (j >= 64) return;
    const float invN = 1.0f / (float)NN;
    float mu = st[512 + j] * invN;
    float var = st[576 + j] * invN - mu * mu;
    float a = g_bn[j] * rsqrtf(var + EPS);
    st[640 + j] = a;
    st[704 + j] = be_bn[j] - a * mu;
}

__global__ __launch_bounds__(256) void k_final4(const float4* __restrict__ nf4,
                                                float4* __restrict__ io4,
                                                const float* __restrict__ st)
{
    long i = (long)blockIdx.x * blockDim.x + threadIdx.x;
    if (i >= (long)NN * 16) return;
    int j4 = ((int)i & 15) * 4;
    float4 n = nf4[i];
    float4 v = io4[i];
    float4 o;
    o.x = softplus_f(n.x + fmaf(st[640 + j4 + 0], v.x, st[704 + j4 + 0]));
    o.y = softplus_f(n.y + fmaf(st[640 + j4 + 1], v.y, st[704 + j4 + 1]));
    o.z = softplus_f(n.z + fmaf(st[640 + j4 + 2], v.z, st[704 + j4 + 2]));
    o.w = softplus_f(n.w + fmaf(st[640 + j4 + 3], v.w, st[704 + j4 + 3]));
    io4[i] = o;
}

extern "C" void kernel_launch(void* const* d_in, const int* in_sizes, int n_in,
                              void* d_out, int out_size, void* d_ws, size_t ws_size,
                              hipStream_t stream) {
    const float* nf  = (const float*)d_in[0];
    const float* ef  = (const float*)d_in[1];
    const int*   src = (const int*)d_in[2];
    const int*   dst = (const int*)d_in[3];
    const float* Wi  = (const float*)d_in[4];
    const float* bi  = (const float*)d_in[5];
    const float* gi  = (const float*)d_in[6];
    const float* bei = (const float*)d_in[7];
    const float* Wu  = (const float*)d_in[8];
    const float* bu  = (const float*)d_in[9];
    const float* gu  = (const float*)d_in[10];
    const float* beu = (const float*)d_in[11];
    const float* gbn = (const float*)d_in[12];
    const float* bebn= (const float*)d_in[13];
    float* out = (float*)d_out;

    // ws (u32): P[NN*64] Q[NN*64] st[1024] cnt[NN+8] cur[NN] bsum[128] srcSE[2*(NE+16)]
    unsigned* P    = (unsigned*)d_ws;
    unsigned* Q    = P + (size_t)NN * 64;
    float*    st   = (float*)(Q + (size_t)NN * 64);
    unsigned* cnt  = (unsigned*)(st + 1024);
    unsigned* cur  = cnt + (NN + 8);
    unsigned* bsum = cur + NN;
    int2* srcSE = (int2*)(bsum + 128);

    const size_t NEEDED_CSR =
        ((size_t)NN * 128 + 1024 + (NN + 8) + NN + 128 + 2 * ((size_t)NE + 16)) * 4;
    const bool use_csr = (ws_size >= NEEDED_CSR);

    hipMemsetAsync(st, 0, 1024 * sizeof(float), stream);

    if (use_csr) {
        hipMemsetAsync(cnt, 0, (size_t)(NN + 8) * sizeof(unsigned), stream);
        k_nodes_mfma<<<512, 256, 0, stream>>>(nf, Wi, Wu, bi, bu, dst, cnt, P, Q);
        k_scan1<<<SCAN_NB, 1024, 0, stream>>>(cnt, bsum);
        k_scan2<<<1, 128, 0, stream>>>(bsum, cnt);
        k_scan3<<<SCAN_NB, 1024, 0, stream>>>(cnt, bsum, cur);
        k_scatter<<<1024, 256, 0, stream>>>(src, dst, cur, srcSE);
        k_edge<true, SAMPLE><<<1024, 256, 0, stream>>>(ef, src, dst, Wi, Wu, P, Q, st, out);
        k_bn_edge<<<1, 128, 0, stream>>>(gi, bei, gu, beu, st);
        k_flat<<<(NGROUP + 3) / 4, 256, 0, stream>>>(ef, srcSE, cnt, Wi, Wu, P, Q, st, out);
        k_bn_node<<<1, 64, 0, stream>>>(gbn, bebn, st);
    } else {
        k_nodes_mfma<<<512, 256, 0, stream>>>(nf, Wi, Wu, bi, bu, nullptr, nullptr, P, Q);
        hipMemsetAsync(d_out, 0, (size_t)out_size * sizeof(float), stream);
        k_edge<true, SAMPLE><<<1024, 256, 0, stream>>>(ef, src, dst, Wi, Wu, P, Q, st, out);
        k_bn_edge<<<1, 128, 0, stream>>>(gi, bei, gu, beu, st);
        k_edge<false, 1><<<2048, 256, 0, stream>>>(ef, src, dst, Wi, Wu, P, Q, st, out);
        k_node_stats<<<512, 256, 0, stream>>>(out, st);
        k_bn_node<<<1, 64, 0, stream>>>(gbn, bebn, st);
    }

    long tot4 = (long)NN * 16;
    k_final4<<<(int)((tot4 + 255) / 256), 256, 0, stream>>>(
        (const float4*)nf, (float4*)out, st);
}

// Round 14
// 439.810 us; speedup vs baseline: 1.4684x; 1.0879x over previous
//
#include <hip/hip_runtime.h>
#include <hip/hip_bf16.h>

#define NN 100000
#define NE 1600000
#define FN 64
#define FE 32
#define EPS 1e-5f
#define SAMPLE 16
#define SAMPLED_E (NE / SAMPLE)
#define SCAN_NB 98
#define GNODES 8
#define NGROUP (NN / GNODES)

typedef __attribute__((ext_vector_type(8))) short bf16x8;
typedef __attribute__((ext_vector_type(4))) float f32x4;

__device__ __forceinline__ float softplus_f(float x) {
    return log1pf(expf(-fabsf(x))) + fmaxf(x, 0.0f);
}
__device__ __forceinline__ float sigmoid_fast(float x) {
    return __builtin_amdgcn_rcpf(1.0f + __expf(-x));
}
__device__ __forceinline__ float softplus_fast(float x) {
    return __logf(1.0f + __expf(-fabsf(x))) + fmaxf(x, 0.0f);
}
__device__ __forceinline__ short f2bf(float f) {
    __hip_bfloat16 h = __float2bfloat16(f);
    return *reinterpret_cast<short*>(&h);
}
__device__ __forceinline__ unsigned pack_bf2(float lo, float hi) {
    __hip_bfloat162 t = __float22bfloat162_rn(float2{lo, hi});
    return *(unsigned*)&t;
}
__device__ __forceinline__ float bflo(unsigned w) { return __uint_as_float(w << 16); }
__device__ __forceinline__ float bfhi(unsigned w) { return __uint_as_float(w & 0xffff0000u); }

// st layout: 0:s_i 64:ss_i 128:s_u 192:ss_u 256:sc_i 320:sh_i 384:sc_u 448:sh_u
//            512:s_bn 576:ss_bn 640:a_bn 704:c_bn

// ---------- node precompute via MFMA (pure GEMM; hist un-fused per r13 post-mortem) ----------
__global__ __launch_bounds__(256) void k_nodes_mfma(
    const float* __restrict__ nf,
    const float* __restrict__ Wi, const float* __restrict__ Wu,
    const float* __restrict__ bi, const float* __restrict__ bu,
    unsigned* __restrict__ P, unsigned* __restrict__ Q)
{
    const int lane = threadIdx.x & 63;
    const int l15 = lane & 15;
    const int lh  = lane >> 4;
    const int wave = threadIdx.x >> 6;
    const long wid = (long)blockIdx.x * 4 + wave;
    const long nwaves = (long)gridDim.x * 4;

    bf16x8 B[2][2][4][2];
    #pragma unroll
    for (int mi = 0; mi < 2; ++mi) {
        const float* W = mi ? Wu : Wi;
        #pragma unroll
        for (int h = 0; h < 2; ++h)
        #pragma unroll
        for (int c = 0; c < 4; ++c)
        #pragma unroll
        for (int ks = 0; ks < 2; ++ks)
        #pragma unroll
        for (int j = 0; j < 8; ++j) {
            int row = h * 64 + ks * 32 + lh * 8 + j;
            int col = c * 16 + l15;
            B[mi][h][c][ks][j] = f2bf(W[row * 64 + col]);
        }
    }
    float bic[4], buc[4];
    #pragma unroll
    for (int c = 0; c < 4; ++c) { bic[c] = bi[c * 16 + l15]; buc[c] = bu[c * 16 + l15]; }

    const f32x4 zero = {0.f, 0.f, 0.f, 0.f};
    for (long g = wid; g < NN / 16; g += nwaves) {
        const long n0 = g * 16;
        const float* arow = nf + (n0 + l15) * 64 + lh * 8;
        float4 a00 = *(const float4*)(arow);
        float4 a01 = *(const float4*)(arow + 4);
        float4 a10 = *(const float4*)(arow + 32);
        float4 a11 = *(const float4*)(arow + 36);
        bf16x8 A0, A1;
        A0[0] = f2bf(a00.x); A0[1] = f2bf(a00.y); A0[2] = f2bf(a00.z); A0[3] = f2bf(a00.w);
        A0[4] = f2bf(a01.x); A0[5] = f2bf(a01.y); A0[6] = f2bf(a01.z); A0[7] = f2bf(a01.w);
        A1[0] = f2bf(a10.x); A1[1] = f2bf(a10.y); A1[2] = f2bf(a10.z); A1[3] = f2bf(a10.w);
        A1[4] = f2bf(a11.x); A1[5] = f2bf(a11.y); A1[6] = f2bf(a11.z); A1[7] = f2bf(a11.w);

        f32x4 acc[2][2][4];
        #pragma unroll
        for (int mi = 0; mi < 2; ++mi)
        #pragma unroll
        for (int h = 0; h < 2; ++h)
        #pragma unroll
        for (int c = 0; c < 4; ++c) {
            f32x4 t = __builtin_amdgcn_mfma_f32_16x16x32_bf16(A0, B[mi][h][c][0], zero, 0, 0, 0);
            acc[mi][h][c] = __builtin_amdgcn_mfma_f32_16x16x32_bf16(A1, B[mi][h][c][1], t, 0, 0, 0);
        }
        #pragma unroll
        for (int r = 0; r < 4; ++r) {
            uint4 wp, wq;
            unsigned* pw = (unsigned*)&wp;
            unsigned* qw = (unsigned*)&wq;
            #pragma unroll
            for (int c = 0; c < 4; ++c) {
                pw[c] = pack_bf2(acc[0][0][c][r] + bic[c], acc[1][0][c][r] + buc[c]);
                qw[c] = pack_bf2(acc[0][1][c][r], acc[1][1][c][r]);
            }
            *(uint4*)(P + (n0 + lh * 4 + r) * 64 + l15 * 4) = wp;
            *(uint4*)(Q + (n0 + lh * 4 + r) * 64 + l15 * 4) = wq;
        }
    }
}

// ---------- standalone histogram (full-TLP; proven r11 ~25 us) ----------
__global__ __launch_bounds__(256) void k_hist(const int* __restrict__ dst,
                                              unsigned* __restrict__ cnt)
{
    long i = (long)blockIdx.x * blockDim.x + threadIdx.x;
    long stride = (long)gridDim.x * blockDim.x;
    for (long e = i; e < NE / 4; e += stride) {
        int4 d = ((const int4*)dst)[e];
        atomicAdd(&cnt[d.x], 1u);
        atomicAdd(&cnt[d.y], 1u);
        atomicAdd(&cnt[d.z], 1u);
        atomicAdd(&cnt[d.w], 1u);
    }
}

// ---------- multi-block scan (proven r11/r13) ----------
__global__ __launch_bounds__(1024) void k_scan1(unsigned* __restrict__ cnt,
                                                unsigned* __restrict__ bsum)
{
    __shared__ unsigned s[1024];
    int t = threadIdx.x;
    long idx = (long)blockIdx.x * 1024 + t;
    unsigned v = (idx < NN) ? cnt[idx] : 0u;
    s[t] = v;
    __syncthreads();
    #pragma unroll
    for (int off = 1; off < 1024; off <<= 1) {
        unsigned add = (t >= off) ? s[t - off] : 0u;
        __syncthreads();
        s[t] += add;
        __syncthreads();
    }
    if (idx < NN) cnt[idx] = s[t] - v;
    if (t == 1023) bsum[blockIdx.x] = s[1023];
}

__global__ void k_scan2(unsigned* __restrict__ bsum, unsigned* __restrict__ cnt)
{
    __shared__ unsigned s[128];
    int t = threadIdx.x;
    unsigned v = (t < SCAN_NB) ? bsum[t] : 0u;
    s[t] = v;
    __syncthreads();
    #pragma unroll
    for (int off = 1; off < 128; off <<= 1) {
        unsigned add = (t >= off) ? s[t - off] : 0u;
        __syncthreads();
        s[t] += add;
        __syncthreads();
    }
    if (t < SCAN_NB) bsum[t] = s[t] - v;
    if (t == 127) cnt[NN] = NE;             // CSR sentinel
}

__global__ __launch_bounds__(1024) void k_scan3(unsigned* __restrict__ cnt,
                                                const unsigned* __restrict__ bsum,
                                                unsigned* __restrict__ cur)
{
    long idx = (long)blockIdx.x * 1024 + threadIdx.x;
    if (idx < NN) {
        unsigned v = cnt[idx] + bsum[blockIdx.x];
        cnt[idx] = v;
        cur[idx] = v;
    }
}

// ---------- scatter: one int2 (8B) store per edge ----------
__global__ __launch_bounds__(256) void k_scatter(const int* __restrict__ src,
                                                 const int* __restrict__ dst,
                                                 unsigned* __restrict__ cur,
                                                 int2* __restrict__ srcSE)
{
    long i = (long)blockIdx.x * blockDim.x + threadIdx.x;
    long stride = (long)gridDim.x * blockDim.x;
    for (long e = i; e < NE; e += stride) {
        int s = src[e], d = dst[e];
        unsigned pos = atomicAdd(&cur[d], 1u);
        srcSE[pos] = make_int2(s | ((d & 7) << 20), (int)e);
    }
}

// ---------- flat-tile grouped-CSR apply + fused node-BN stats ----------
__global__ __launch_bounds__(256) void k_flat(
    const float* __restrict__ ef,
    const int2* __restrict__ srcSE,
    const unsigned* __restrict__ roff,
    const float* __restrict__ Wi, const float* __restrict__ Wu,
    const unsigned* __restrict__ P, const unsigned* __restrict__ Q,
    float* __restrict__ st, float* __restrict__ agg)
{
    const int lane = threadIdx.x & 63;
    const int l15 = lane & 15;
    const int lh  = lane >> 4;
    const int wave = threadIdx.x >> 6;
    const int wid = blockIdx.x * 4 + wave;
    const int nwaves = gridDim.x * 4;

    __shared__ float slab[4][GNODES][64];
    __shared__ float red[256][2];

    bf16x8 Bi[4], Bu[4];
    #pragma unroll
    for (int c = 0; c < 4; ++c) {
        #pragma unroll
        for (int j = 0; j < 8; ++j) {
            int row = 128 + lh * 8 + j;
            int col = c * 16 + l15;
            Bi[c][j] = f2bf(Wi[row * 64 + col]);
            Bu[c][j] = f2bf(Wu[row * 64 + col]);
        }
    }
    float sci[4], shi[4], scu[4], shu[4];
    #pragma unroll
    for (int c = 0; c < 4; ++c) {
        int col = c * 16 + l15;
        sci[c] = st[256 + col]; shi[c] = st[320 + col];
        scu[c] = st[384 + col]; shu[c] = st[448 + col];
    }

    float sb = 0.f, ssb = 0.f;
    const f32x4 zero = {0.f, 0.f, 0.f, 0.f};

    for (int g = wid; g < NGROUP; g += nwaves) {
        const int n0 = g * GNODES;

        #pragma unroll
        for (int k = 0; k < GNODES; ++k) slab[wave][k][lane] = 0.f;

        const int lo = (int)roff[n0];
        const int hi = (int)roff[n0 + GNODES];

        if (lo < hi) {
            const int hiM1 = hi - 1;
            const int ntile = (hi - lo + 15) >> 4;

            int sC[4], eidC;
            uint4 pvC[4];
            float4 efC0, efC1;
            {
                #pragma unroll
                for (int r = 0; r < 4; ++r) {
                    int e = lo + lh * 4 + r;
                    sC[r] = srcSE[e < hi ? e : hiM1].x;
                }
                int ei = lo + l15;
                eidC = srcSE[ei < hi ? ei : hiM1].y;
                #pragma unroll
                for (int r = 0; r < 4; ++r)
                    pvC[r] = *(const uint4*)(P + (long)(sC[r] & 0xFFFFF) * 64 + l15 * 4);
                const float* efr = ef + (long)eidC * FE + lh * 8;
                efC0 = *(const float4*)(efr);
                efC1 = *(const float4*)(efr + 4);
            }
            int sN[4], eidN;
            {
                const int base1 = (ntile > 1) ? lo + 16 : lo;
                #pragma unroll
                for (int r = 0; r < 4; ++r) {
                    int e = base1 + lh * 4 + r;
                    sN[r] = srcSE[e < hi ? e : hiM1].x;
                }
                int ei = base1 + l15;
                eidN = srcSE[ei < hi ? ei : hiM1].y;
            }

            for (int ti = 0; ti < ntile; ++ti) {
                const int base = lo + ti * 16;
                uint4 pvN[4];
                float4 efN0, efN1;
                #pragma unroll
                for (int r = 0; r < 4; ++r)
                    pvN[r] = *(const uint4*)(P + (long)(sN[r] & 0xFFFFF) * 64 + l15 * 4);
                {
                    const float* efr = ef + (long)eidN * FE + lh * 8;
                    efN0 = *(const float4*)(efr);
                    efN1 = *(const float4*)(efr + 4);
                }
                int nid[4];
                uint4 qv[4];
                #pragma unroll
                for (int r = 0; r < 4; ++r) {
                    nid[r] = (sC[r] >> 20) & 7;
                    qv[r] = *(const uint4*)(Q + (long)(n0 + nid[r]) * 64 + l15 * 4);
                }
                int sN2[4], eidN2;
                {
                    int t2 = ti + 2;
                    t2 = (t2 < ntile) ? t2 : ntile - 1;
                    const int base2 = lo + t2 * 16;
                    #pragma unroll
                    for (int r = 0; r < 4; ++r) {
                        int e = base2 + lh * 4 + r;
                        sN2[r] = srcSE[e < hi ? e : hiM1].x;
                    }
                    int ei = base2 + l15;
                    eidN2 = srcSE[ei < hi ? ei : hiM1].y;
                }

                bf16x8 A;
                A[0] = f2bf(efC0.x); A[1] = f2bf(efC0.y); A[2] = f2bf(efC0.z); A[3] = f2bf(efC0.w);
                A[4] = f2bf(efC1.x); A[5] = f2bf(efC1.y); A[6] = f2bf(efC1.z); A[7] = f2bf(efC1.w);

                float vm[4];
                #pragma unroll
                for (int r = 0; r < 4; ++r)
                    vm[r] = (base + lh * 4 + r < hi) ? 1.0f : 0.0f;
                bool f1 = (nid[1] != nid[0]);
                bool f2 = (nid[2] != nid[1]);
                bool f3 = (nid[3] != nid[2]);

                #pragma unroll
                for (int c = 0; c < 4; ++c) {
                    f32x4 Ei = __builtin_amdgcn_mfma_f32_16x16x32_bf16(A, Bi[c], zero, 0, 0, 0);
                    f32x4 Eu = __builtin_amdgcn_mfma_f32_16x16x32_bf16(A, Bu[c], zero, 0, 0, 0);
                    const int col = c * 16 + l15;
                    float av = 0.f;
                    #pragma unroll
                    for (int r = 0; r < 4; ++r) {
                        unsigned qw = ((const unsigned*)&qv[r])[c];
                        unsigned pw = ((const unsigned*)&pvC[r])[c];
                        float ai = bflo(pw) + bflo(qw) + Ei[r];
                        float au = bfhi(pw) + bfhi(qw) + Eu[r];
                        float gate = sigmoid_fast(fmaf(sci[c], ai, shi[c]));
                        float updv = softplus_fast(fmaf(scu[c], au, shu[c]));
                        float val = gate * updv * vm[r];
                        if (r == 1 && f1) { atomicAdd(&slab[wave][nid[0]][col], av); av = 0.f; }
                        if (r == 2 && f2) { atomicAdd(&slab[wave][nid[1]][col], av); av = 0.f; }
                        if (r == 3 && f3) { atomicAdd(&slab[wave][nid[2]][col], av); av = 0.f; }
                        av += val;
                    }
                    atomicAdd(&slab[wave][nid[3]][col], av);
                }

                #pragma unroll
                for (int r = 0; r < 4; ++r) { pvC[r] = pvN[r]; sC[r] = sN[r]; sN[r] = sN2[r]; }
                efC0 = efN0; efC1 = efN1;
                eidC = eidN; eidN = eidN2;
            }
        }

        #pragma unroll
        for (int k = 0; k < GNODES; ++k) {
            float v = slab[wave][k][lane];
            agg[(long)(n0 + k) * 64 + lane] = v;
            sb += v; ssb = fmaf(v, v, ssb);
        }
    }

    red[threadIdx.x][0] = sb;
    red[threadIdx.x][1] = ssb;
    __syncthreads();
    if (threadIdx.x < 64) {
        float a = 0.f, bb = 0.f;
        #pragma unroll
        for (int w = 0; w < 4; ++w) {
            a  += red[w * 64 + threadIdx.x][0];
            bb += red[w * 64 + threadIdx.x][1];
        }
        atomicAdd(&st[512 + threadIdx.x], a);
        atomicAdd(&st[576 + threadIdx.x], bb);
    }
}

// ---------- stats / fallback edge kernel (unsorted, depth-2 pipeline) ----------
template <bool STATS, int GSTRIDE>
__global__ __launch_bounds__(256) void k_edge(
    const float* __restrict__ ef,
    const int* __restrict__ src, const int* __restrict__ dst,
    const float* __restrict__ Wi, const float* __restrict__ Wu,
    const unsigned* __restrict__ P, const unsigned* __restrict__ Q,
    float* __restrict__ st, float* __restrict__ agg)
{
    const int lane = threadIdx.x & 63;
    const int l15 = lane & 15;
    const int lh  = lane >> 4;
    const int wave = threadIdx.x >> 6;
    const long wid = (long)blockIdx.x * 4 + wave;
    const long nwaves = (long)gridDim.x * 4;

    __shared__ float accs[4][64];
    if (STATS) {
        if (threadIdx.x < 256) ((float*)accs)[threadIdx.x] = 0.f;
        __syncthreads();
    }

    bf16x8 Bi[4], Bu[4];
    #pragma unroll
    for (int c = 0; c < 4; ++c) {
        #pragma unroll
        for (int j = 0; j < 8; ++j) {
            int row = 128 + lh * 8 + j;
            int col = c * 16 + l15;
            Bi[c][j] = f2bf(Wi[row * 64 + col]);
            Bu[c][j] = f2bf(Wu[row * 64 + col]);
        }
    }
    float sci[4], shi[4], scu[4], shu[4];
    #pragma unroll
    for (int c = 0; c < 4; ++c) {
        int col = c * 16 + l15;
        if (!STATS) {
            sci[c] = st[256 + col]; shi[c] = st[320 + col];
            scu[c] = st[384 + col]; shu[c] = st[448 + col];
        } else {
            sci[c] = shi[c] = scu[c] = shu[c] = 0.f;
        }
    }

    float s_i[4] = {0,0,0,0}, ss_i[4] = {0,0,0,0};
    float s_u[4] = {0,0,0,0}, ss_u[4] = {0,0,0,0};

    const long NGI = (NE / 16) / GSTRIDE;
    if (wid < NGI) {
        const long gi0 = wid;
        const long e00 = gi0 * GSTRIDE * 16;
        int4 sC = *(const int4*)(src + e00 + lh * 4);
        int4 dC = *(const int4*)(dst + e00 + lh * 4);
        uint4 pvC[4], qvC[4];
        {
            int sA[4] = {sC.x, sC.y, sC.z, sC.w};
            int dA[4] = {dC.x, dC.y, dC.z, dC.w};
            #pragma unroll
            for (int r = 0; r < 4; ++r) {
                pvC[r] = *(const uint4*)(P + (long)sA[r] * 64 + l15 * 4);
                qvC[r] = *(const uint4*)(Q + (long)dA[r] * 64 + l15 * 4);
            }
        }
        float4 efC0 = *(const float4*)(ef + (e00 + l15) * FE + lh * 8);
        float4 efC1 = *(const float4*)(ef + (e00 + l15) * FE + lh * 8 + 4);

        long g1p = gi0 + nwaves;
        long g1c = (g1p < NGI) ? g1p : gi0;
        int4 sN = *(const int4*)(src + g1c * GSTRIDE * 16 + lh * 4);
        int4 dN = *(const int4*)(dst + g1c * GSTRIDE * 16 + lh * 4);

        for (long gi = gi0; gi < NGI; gi += nwaves) {
            const long gn   = gi + nwaves;
            const long gnc  = (gn < NGI) ? gn : gi;
            const long gn2  = gn + nwaves;
            const long gn2c = (gn2 < NGI) ? gn2 : gnc;
            const long eN  = gnc * GSTRIDE * 16;
            const long eN2 = gn2c * GSTRIDE * 16;

            uint4 pvN[4], qvN[4];
            {
                int sA[4] = {sN.x, sN.y, sN.z, sN.w};
                int dA[4] = {dN.x, dN.y, dN.z, dN.w};
                #pragma unroll
                for (int r = 0; r < 4; ++r) {
                    pvN[r] = *(const uint4*)(P + (long)sA[r] * 64 + l15 * 4);
                    qvN[r] = *(const uint4*)(Q + (long)dA[r] * 64 + l15 * 4);
                }
            }
            float4 efN0 = *(const float4*)(ef + (eN + l15) * FE + lh * 8);
            float4 efN1 = *(const float4*)(ef + (eN + l15) * FE + lh * 8 + 4);
            int4 sN2 = *(const int4*)(src + eN2 + lh * 4);
            int4 dN2 = *(const int4*)(dst + eN2 + lh * 4);

            bf16x8 A;
            A[0] = f2bf(efC0.x); A[1] = f2bf(efC0.y); A[2] = f2bf(efC0.z); A[3] = f2bf(efC0.w);
            A[4] = f2bf(efC1.x); A[5] = f2bf(efC1.y); A[6] = f2bf(efC1.z); A[7] = f2bf(efC1.w);
            int dApply[4] = {dC.x, dC.y, dC.z, dC.w};

            const f32x4 zero = {0.f, 0.f, 0.f, 0.f};
            #pragma unroll
            for (int c = 0; c < 4; ++c) {
                f32x4 Ei = __builtin_amdgcn_mfma_f32_16x16x32_bf16(A, Bi[c], zero, 0, 0, 0);
                f32x4 Eu = __builtin_amdgcn_mfma_f32_16x16x32_bf16(A, Bu[c], zero, 0, 0, 0);
                #pragma unroll
                for (int r = 0; r < 4; ++r) {
                    unsigned pw = ((const unsigned*)&pvC[r])[c];
                    unsigned qw = ((const unsigned*)&qvC[r])[c];
                    float ai = bflo(pw) + bflo(qw) + Ei[r];
                    float au = bfhi(pw) + bfhi(qw) + Eu[r];
                    if constexpr (STATS) {
                        s_i[c] += ai; ss_i[c] = fmaf(ai, ai, ss_i[c]);
                        s_u[c] += au; ss_u[c] = fmaf(au, au, ss_u[c]);
                    } else {
                        float gate = sigmoid_fast(fmaf(sci[c], ai, shi[c]));
                        float updv = softplus_fast(fmaf(scu[c], au, shu[c]));
                        atomicAdd(&agg[(long)dApply[r] * 64 + c * 16 + l15], gate * updv);
                    }
                }
            }

            #pragma unroll
            for (int r = 0; r < 4; ++r) { pvC[r] = pvN[r]; qvC[r] = qvN[r]; }
            efC0 = efN0; efC1 = efN1;
            dC = dN;
            sN = sN2; dN = dN2;
        }
    }

    if (STATS) {
        #pragma unroll
        for (int c = 0; c < 4; ++c) {
            int col = c * 16 + l15;
            atomicAdd(&accs[0][col], s_i[c]);
            atomicAdd(&accs[1][col], ss_i[c]);
            atomicAdd(&accs[2][col], s_u[c]);
            atomicAdd(&accs[3][col], ss_u[c]);
        }
        __syncthreads();
        {
            int stn = threadIdx.x >> 6, col = threadIdx.x & 63;
            atomicAdd(&st[stn * 64 + col], accs[stn][col]);
        }
    }
}

// ---------- small kernels ----------
__global__ void k_bn_edge(const float* __restrict__ g_i, const float* __restrict__ be_i,
                          const float* __restrict__ g_u, const float* __restrict__ be_u,
                          float* __restrict__ st)
{
    int j = threadIdx.x & 63;
    int br = threadIdx.x >> 6;
    const float invE = 1.0f / (float)SAMPLED_E;
    float s  = st[br * 128 + j];
    float ss = st[br * 128 + 64 + j];
    float mu = s * invE;
    float var = ss * invE - mu * mu;
    float inv = rsqrtf(var + EPS);
    float g  = br ? g_u[j]  : g_i[j];
    float be = br ? be_u[j] : be_i[j];
    float a = g * inv;
    st[256 + br * 128 + j]      = a;
    st[256 + br * 128 + 64 + j] = be - a * mu;
}

__global__ __launch_bounds__(256) void k_node_stats(const float* __restrict__ agg,
                                                    float* __restrict__ st)
{
    int lane = threadIdx.x & 63;
    int wave = threadIdx.x >> 6;
    float s = 0.f, ss = 0.f;
    for (long r = (long)blockIdx.x * 4 + wave; r < NN; r += (long)gridDim.x * 4) {
        float v = agg[r * 64 + lane];
        s += v; ss += v * v;
    }
    __shared__ float red[256][2];
    red[threadIdx.x][0] = s; red[threadIdx.x][1] = ss;
    __syncthreads();
    if (threadIdx.x < 64) {
        float a = 0.f, b = 0.f;
        for (int w = 0; w < 4; ++w) {
            a += red[w * 64 + threadIdx.x][0];
            b += red[w * 64 + threadIdx.x][1];
        }
        atomicAdd(&st[512 + threadIdx.x], a);
        atomicAdd(&st[576 + threadIdx.x], b);
    }
}

__global__ void k_bn_node(const float* __restrict__ g_bn, const float* __restrict__ be_bn,
                          float* __restrict__ st)
{
    int j = threadIdx.x;
    if (j >= 64) return;
    const float invN = 1.0f / (float)NN;
    float mu = st[512 + j] * invN;
    float var = st[576 + j] * invN - mu * mu;
    float a = g_bn[j] * rsqrtf(var + EPS);
    st[640 + j] = a;
    st[704 + j] = be_bn[j] - a * mu;
}

__global__ __launch_bounds__(256) void k_final4(const float4* __restrict__ nf4,
                                                float4* __restrict__ io4,
                                                const float* __restrict__ st)
{
    long i = (long)blockIdx.x * blockDim.x + threadIdx.x;
    if (i >= (long)NN * 16) return;
    int j4 = ((int)i & 15) * 4;
    float4 n = nf4[i];
    float4 v = io4[i];
    float4 o;
    o.x = softplus_f(n.x + fmaf(st[640 + j4 + 0], v.x, st[704 + j4 + 0]));
    o.y = softplus_f(n.y + fmaf(st[640 + j4 + 1], v.y, st[704 + j4 + 1]));
    o.z = softplus_f(n.z + fmaf(st[640 + j4 + 2], v.z, st[704 + j4 + 2]));
    o.w = softplus_f(n.w + fmaf(st[640 + j4 + 3], v.w, st[704 + j4 + 3]));
    io4[i] = o;
}

extern "C" void kernel_launch(void* const* d_in, const int* in_sizes, int n_in,
                              void* d_out, int out_size, void* d_ws, size_t ws_size,
                              hipStream_t stream) {
    const float* nf  = (const float*)d_in[0];
    const float* ef  = (const float*)d_in[1];
    const int*   src = (const int*)d_in[2];
    const int*   dst = (const int*)d_in[3];
    const float* Wi  = (const float*)d_in[4];
    const float* bi  = (const float*)d_in[5];
    const float* gi  = (const float*)d_in[6];
    const float* bei = (const float*)d_in[7];
    const float* Wu  = (const float*)d_in[8];
    const float* bu  = (const float*)d_in[9];
    const float* gu  = (const float*)d_in[10];
    const float* beu = (const float*)d_in[11];
    const float* gbn = (const float*)d_in[12];
    const float* bebn= (const float*)d_in[13];
    float* out = (float*)d_out;

    // ws (u32): P[NN*64] Q[NN*64] st[1024] cnt[NN+8] cur[NN] bsum[128] srcSE[2*(NE+16)]
    unsigned* P    = (unsigned*)d_ws;
    unsigned* Q    = P + (size_t)NN * 64;
    float*    st   = (float*)(Q + (size_t)NN * 64);
    unsigned* cnt  = (unsigned*)(st + 1024);
    unsigned* cur  = cnt + (NN + 8);
    unsigned* bsum = cur + NN;
    int2* srcSE = (int2*)(bsum + 128);

    const size_t NEEDED_CSR =
        ((size_t)NN * 128 + 1024 + (NN + 8) + NN + 128 + 2 * ((size_t)NE + 16)) * 4;
    const bool use_csr = (ws_size >= NEEDED_CSR);

    hipMemsetAsync(st, 0, 1024 * sizeof(float), stream);

    if (use_csr) {
        hipMemsetAsync(cnt, 0, (size_t)(NN + 8) * sizeof(unsigned), stream);
        k_nodes_mfma<<<512, 256, 0, stream>>>(nf, Wi, Wu, bi, bu, P, Q);
        k_hist<<<1024, 256, 0, stream>>>(dst, cnt);
        k_scan1<<<SCAN_NB, 1024, 0, stream>>>(cnt, bsum);
        k_scan2<<<1, 128, 0, stream>>>(bsum, cnt);
        k_scan3<<<SCAN_NB, 1024, 0, stream>>>(cnt, bsum, cur);
        k_scatter<<<1024, 256, 0, stream>>>(src, dst, cur, srcSE);
        k_edge<true, SAMPLE><<<1024, 256, 0, stream>>>(ef, src, dst, Wi, Wu, P, Q, st, out);
        k_bn_edge<<<1, 128, 0, stream>>>(gi, bei, gu, beu, st);
        k_flat<<<(NGROUP + 3) / 4, 256, 0, stream>>>(ef, srcSE, cnt, Wi, Wu, P, Q, st, out);
        k_bn_node<<<1, 64, 0, stream>>>(gbn, bebn, st);
    } else {
        k_nodes_mfma<<<512, 256, 0, stream>>>(nf, Wi, Wu, bi, bu, P, Q);
        hipMemsetAsync(d_out, 0, (size_t)out_size * sizeof(float), stream);
        k_edge<true, SAMPLE><<<1024, 256, 0, stream>>>(ef, src, dst, Wi, Wu, P, Q, st, out);
        k_bn_edge<<<1, 128, 0, stream>>>(gi, bei, gu, beu, st);
        k_edge<false, 1><<<2048, 256, 0, stream>>>(ef, src, dst, Wi, Wu, P, Q, st, out);
        k_node_stats<<<512, 256, 0, stream>>>(out, st);
        k_bn_node<<<1, 64, 0, stream>>>(gbn, bebn, st);
    }

    long tot4 = (long)NN * 16;
    k_final4<<<(int)((tot4 + 255) / 256), 256, 0, stream>>>(
        (const float4*)nf, (float4*)out, st);
}